// Round 5
// baseline (881.813 us; speedup 1.0000x reference)
//
#include <hip/hip_runtime.h>

// LightGCN propagation on MI355X — R4: row-histogram CSR offsets + 256-row
// bucket partition + single-pass per-bucket sort + unrolled bf16 gather SpMM.
//
// R3 post-mortem: k_part 172 us (WRITE 181 MB = 3.8x amp from 62B runs at 1024
// blocks); k_sort did 2 passes over pairs1. R4: buckets of 256 rows (shift math),
// full row_ptr from a global row histogram + two-level scan (aligned 1:1 with
// buckets), k_sort loads cursors from row_ptr (1 pass), PART_BLOCKS=512 for
// ~160B runs, unroll-2 placement loops, unroll-4 SpMM gather.
//
// Inputs: [2] adj_src (6M int), [3] adj_dst (6M int), [4] adj_vals (6M f32),
//         [5] user_emb (100000x64 f32), [6] item_emb (50000x64 f32).
// Output: [150000x64] f32 = (e0+e1+e2+e3)/4.

#define NUM_USERS 100000
#define NUM_ITEMS 50000
#define N_NODES   150000
#define EMB       64
#define N_EDGES   6000000

#define ROWS_PER_B 256
#define NBUCKET    587            // ceil(150000/256) = 586 buckets; +1 pad unused
#define NBUCKETS   586
#define NROWS_PAD  (NBUCKETS * ROWS_PER_B)   // 150016
#define PART_BLOCKS 512
#define CHUNK ((N_EDGES + PART_BLOCKS - 1) / PART_BLOCKS)   // 11719

constexpr int NODE_F4 = N_NODES * EMB / 4;   // 2,400,000
constexpr int USER_F4 = NUM_USERS * EMB / 4; // 1,600,000

__device__ __forceinline__ float bf2f(unsigned short u) {
    union { unsigned int i; float f; } x; x.i = ((unsigned int)u) << 16; return x.f;
}
__device__ __forceinline__ unsigned short f2bf(float f) {
    union { float f; unsigned int i; } x; x.f = f;
    unsigned int b = x.i;
    return (unsigned short)((b + 0x7FFFu + ((b >> 16) & 1u)) >> 16);  // RNE
}

// ---------------- phase 0: row histogram + scans ----------------

__global__ void k_zero(int* __restrict__ p, int n) {
    int i = blockIdx.x * blockDim.x + threadIdx.x;
    if (i < n) p[i] = 0;
}

__global__ void k_hist(const int* __restrict__ dst, int* __restrict__ cnt) {
    int e = blockIdx.x * blockDim.x + threadIdx.x;
    if (e < N_EDGES) atomicAdd(&cnt[dst[e]], 1);   // 600KB counter array, L2-resident
}

// per-bucket (=per-256-row-block) sums
__global__ __launch_bounds__(256) void k_blocksum(const int* __restrict__ cnt,
                                                  int* __restrict__ bsum) {
    __shared__ int s[256];
    int i = blockIdx.x * 256 + threadIdx.x;
    s[threadIdx.x] = (i < NROWS_PAD) ? cnt[i] : 0;
    __syncthreads();
    for (int off = 128; off > 0; off >>= 1) {
        if (threadIdx.x < off) s[threadIdx.x] += s[threadIdx.x + off];
        __syncthreads();
    }
    if (threadIdx.x == 0) bsum[blockIdx.x] = s[0];
}

// one block of 1024: exclusive scan of bucket sums -> boff + gcur
__global__ void k_bscan(const int* __restrict__ bsum, int* __restrict__ boff,
                        int* __restrict__ gcur) {
    __shared__ int s[1024];
    int t = threadIdx.x;
    int x = (t < NBUCKETS) ? bsum[t] : 0;
    s[t] = x;
    __syncthreads();
    for (int off = 1; off < 1024; off <<= 1) {
        int v = (t >= off) ? s[t - off] : 0;
        __syncthreads();
        s[t] += v;
        __syncthreads();
    }
    if (t < NBUCKETS) { int ex = s[t] - x; boff[t] = ex; gcur[t] = ex; }
    if (t == 0) boff[NBUCKETS] = N_EDGES;
}

// per-row exclusive prefix within bucket + boff -> global row_ptr
__global__ __launch_bounds__(256) void k_scan_final(const int* __restrict__ cnt,
                                                    const int* __restrict__ boff,
                                                    int* __restrict__ row_ptr) {
    __shared__ int s[256];
    int b = blockIdx.x;
    int t = threadIdx.x;
    int i = b * 256 + t;
    int x = (i < NROWS_PAD) ? cnt[i] : 0;
    s[t] = x;
    __syncthreads();
    for (int off = 1; off < 256; off <<= 1) {
        int v = (t >= off) ? s[t - off] : 0;
        __syncthreads();
        s[t] += v;
        __syncthreads();
    }
    row_ptr[i] = s[t] - x + boff[b];
    if (b == NBUCKETS - 1 && t == 255) row_ptr[NROWS_PAD] = N_EDGES;
}

// ---------------- phase 1: bucket partition ----------------
// entry: x = src | (dstLocal<<18)  (src<2^18, dstLocal<256), y = val bits

__global__ __launch_bounds__(256) void k_part(const int* __restrict__ src,
                                              const int* __restrict__ dst,
                                              const float* __restrict__ val,
                                              int* __restrict__ gcur,
                                              int2* __restrict__ pairs) {
    __shared__ int cnt[NBUCKETS];
    __shared__ int base[NBUCKETS];
    int t = threadIdx.x;
    for (int i = t; i < NBUCKETS; i += 256) cnt[i] = 0;
    __syncthreads();
    int e0 = blockIdx.x * CHUNK;
    int e1 = min(e0 + CHUNK, N_EDGES);
    {
        int e = e0 + t;
        for (; e + 256 < e1; e += 512) {
            int b0 = dst[e] >> 8;
            int b1 = dst[e + 256] >> 8;
            atomicAdd(&cnt[b0], 1);
            atomicAdd(&cnt[b1], 1);
        }
        if (e < e1) atomicAdd(&cnt[dst[e] >> 8], 1);
    }
    __syncthreads();
    for (int i = t; i < NBUCKETS; i += 256) {
        int c = cnt[i];
        base[i] = c ? (atomicAdd(&gcur[i], c) - 0) : 0;
        cnt[i] = 0;
    }
    __syncthreads();
    {
        int e = e0 + t;
        for (; e + 256 < e1; e += 512) {
            int d0 = dst[e];       int s0 = src[e];       float v0 = val[e];
            int d1 = dst[e + 256]; int s1 = src[e + 256]; float v1 = val[e + 256];
            int b0 = d0 >> 8, b1 = d1 >> 8;
            int o0 = atomicAdd(&cnt[b0], 1);
            int o1 = atomicAdd(&cnt[b1], 1);
            pairs[base[b0] + o0] = make_int2(s0 | ((d0 & 255) << 18), __float_as_int(v0));
            pairs[base[b1] + o1] = make_int2(s1 | ((d1 & 255) << 18), __float_as_int(v1));
        }
        if (e < e1) {
            int d0 = dst[e];
            int o0 = atomicAdd(&cnt[d0 >> 8], 1);
            pairs[base[d0 >> 8] + o0] = make_int2(src[e] | ((d0 & 255) << 18),
                                                  __float_as_int(val[e]));
        }
    }
}

// ---------------- phase 2: per-bucket placement (cursors from row_ptr) ----------------

__global__ __launch_bounds__(256) void k_sort(const int* __restrict__ boff,
                                              const int* __restrict__ row_ptr,
                                              const int2* __restrict__ pairs1,
                                              int2* __restrict__ pairs2) {
    __shared__ int cursor[ROWS_PER_B];
    int b = blockIdx.x;
    int t = threadIdx.x;
    cursor[t] = row_ptr[b * ROWS_PER_B + t];
    __syncthreads();
    int beg = boff[b], end = boff[b + 1];
    int e = beg + t;
    for (; e + 256 < end; e += 512) {
        int2 p0 = pairs1[e];
        int2 p1 = pairs1[e + 256];
        int pos0 = atomicAdd(&cursor[p0.x >> 18], 1);
        int pos1 = atomicAdd(&cursor[p1.x >> 18], 1);
        pairs2[pos0] = make_int2(p0.x & 0x3FFFF, p0.y);
        pairs2[pos1] = make_int2(p1.x & 0x3FFFF, p1.y);
    }
    if (e < end) {
        int2 p0 = pairs1[e];
        int pos0 = atomicAdd(&cursor[p0.x >> 18], 1);
        pairs2[pos0] = make_int2(p0.x & 0x3FFFF, p0.y);
    }
}

// ---------------- phase 3: propagation ----------------

__global__ void k_init(const float4* __restrict__ ue, const float4* __restrict__ ie,
                       ushort4* __restrict__ curb, float4* __restrict__ acc) {
    int i = blockIdx.x * blockDim.x + threadIdx.x;
    if (i >= NODE_F4) return;
    float4 v = (i < USER_F4) ? ue[i] : ie[i - USER_F4];
    acc[i] = v;
    curb[i] = make_ushort4(f2bf(v.x), f2bf(v.y), f2bf(v.z), f2bf(v.w));
}

// 16 lanes per dst row; lane owns 4 channels. bf16 gather, fp32 reg accumulate.
__global__ __launch_bounds__(256) void k_spmm(const int* __restrict__ row_ptr,
                                              const int2* __restrict__ pairs,
                                              const ushort4* __restrict__ cur,
                                              ushort4* __restrict__ nxt,
                                              float4* __restrict__ acc, float s) {
    int tid = blockIdx.x * blockDim.x + threadIdx.x;
    int row = tid >> 4;
    if (row >= N_NODES) return;
    int c = tid & 15;
    int beg = row_ptr[row];
    int end = row_ptr[row + 1];
    float4 r = make_float4(0.f, 0.f, 0.f, 0.f);
    int k = beg;
    for (; k + 3 < end; k += 4) {
        int2 p0 = pairs[k];
        int2 p1 = pairs[k + 1];
        int2 p2 = pairs[k + 2];
        int2 p3 = pairs[k + 3];
        ushort4 g0 = cur[(long)p0.x * 16 + c];
        ushort4 g1 = cur[(long)p1.x * 16 + c];
        ushort4 g2 = cur[(long)p2.x * 16 + c];
        ushort4 g3 = cur[(long)p3.x * 16 + c];
        float v0 = __int_as_float(p0.y);
        float v1 = __int_as_float(p1.y);
        float v2 = __int_as_float(p2.y);
        float v3 = __int_as_float(p3.y);
        r.x += v0 * bf2f(g0.x) + v1 * bf2f(g1.x) + v2 * bf2f(g2.x) + v3 * bf2f(g3.x);
        r.y += v0 * bf2f(g0.y) + v1 * bf2f(g1.y) + v2 * bf2f(g2.y) + v3 * bf2f(g3.y);
        r.z += v0 * bf2f(g0.z) + v1 * bf2f(g1.z) + v2 * bf2f(g2.z) + v3 * bf2f(g3.z);
        r.w += v0 * bf2f(g0.w) + v1 * bf2f(g1.w) + v2 * bf2f(g2.w) + v3 * bf2f(g3.w);
    }
    for (; k < end; ++k) {
        int2 p0 = pairs[k];
        ushort4 g0 = cur[(long)p0.x * 16 + c];
        float v0 = __int_as_float(p0.y);
        r.x += v0 * bf2f(g0.x);
        r.y += v0 * bf2f(g0.y);
        r.z += v0 * bf2f(g0.z);
        r.w += v0 * bf2f(g0.w);
    }
    long o = (long)row * 16 + c;
    nxt[o] = make_ushort4(f2bf(r.x), f2bf(r.y), f2bf(r.z), f2bf(r.w));
    float4 a = acc[o];
    a.x = (a.x + r.x) * s;
    a.y = (a.y + r.y) * s;
    a.z = (a.z + r.z) * s;
    a.w = (a.w + r.w) * s;
    acc[o] = a;
}

// ---------------- R0 fallback (atomic scatter) for small ws ----------------

__global__ void lgcn_init(const float4* __restrict__ user_emb,
                          const float4* __restrict__ item_emb,
                          float4* __restrict__ cur, float4* __restrict__ nxt,
                          float4* __restrict__ acc) {
    int i = blockIdx.x * blockDim.x + threadIdx.x;
    if (i >= NODE_F4) return;
    float4 v = (i < USER_F4) ? user_emb[i] : item_emb[i - USER_F4];
    cur[i] = v; acc[i] = v; nxt[i] = make_float4(0.f, 0.f, 0.f, 0.f);
}

__global__ void lgcn_scatter(const int* __restrict__ src, const int* __restrict__ dst,
                             const float* __restrict__ val,
                             const float4* __restrict__ cur, float* __restrict__ nxt) {
    int tid = blockIdx.x * blockDim.x + threadIdx.x;
    int e = tid >> 4;
    if (e >= N_EDGES) return;
    int c = tid & 15;
    int s = src[e]; int d = dst[e]; float v = val[e];
    float4 m = cur[(long)s * 16 + c];
    float* p = nxt + (long)d * 64 + c * 4;
    unsafeAtomicAdd(p + 0, v * m.x);
    unsafeAtomicAdd(p + 1, v * m.y);
    unsafeAtomicAdd(p + 2, v * m.z);
    unsafeAtomicAdd(p + 3, v * m.w);
}

__global__ void lgcn_add_zero(float4* __restrict__ acc, const float4* __restrict__ nxt,
                              float4* __restrict__ other) {
    int i = blockIdx.x * blockDim.x + threadIdx.x;
    if (i >= NODE_F4) return;
    float4 a = acc[i]; float4 n = nxt[i];
    a.x += n.x; a.y += n.y; a.z += n.z; a.w += n.w;
    acc[i] = a;
    other[i] = make_float4(0.f, 0.f, 0.f, 0.f);
}

__global__ void lgcn_final(float4* __restrict__ acc, const float4* __restrict__ nxt) {
    int i = blockIdx.x * blockDim.x + threadIdx.x;
    if (i >= NODE_F4) return;
    float4 a = acc[i]; float4 n = nxt[i];
    a.x = (a.x + n.x) * 0.25f; a.y = (a.y + n.y) * 0.25f;
    a.z = (a.z + n.z) * 0.25f; a.w = (a.w + n.w) * 0.25f;
    acc[i] = a;
}

// ---------------- launch ----------------

extern "C" void kernel_launch(void* const* d_in, const int* in_sizes, int n_in,
                              void* d_out, int out_size, void* d_ws, size_t ws_size,
                              hipStream_t stream) {
    const int*    adj_src  = (const int*)d_in[2];
    const int*    adj_dst  = (const int*)d_in[3];
    const float*  adj_vals = (const float*)d_in[4];
    const float4* user_emb = (const float4*)d_in[5];
    const float4* item_emb = (const float4*)d_in[6];
    float* acc = (float*)d_out;

    const int BLK = 256;
    const int grid_node  = (NODE_F4 + BLK - 1) / BLK;        // 9375
    const int grid_row16 = (N_NODES * 16 + BLK - 1) / BLK;   // 9375
    const int grid_edge  = (N_EDGES + BLK - 1) / BLK;        // 23438

    // workspace layout (bytes).
    //   [0, 48MB)      pairs2
    //   [48, 96MB)     pairs1; after k_sort reused: curb (19.2MB) + nxtb (19.2MB);
    //                  row_cnt (600KB) lives in its tail [48+40MB, ...) — dead
    //                  before k_part overwrites pairs1.
    //   [96MB, ...)    row_ptr (150017 ints), bsum, boff, gcur
    const size_t SZ_PAIRS = (size_t)N_EDGES * 8;             // 48,000,000
    const size_t SZ_BF    = (size_t)N_NODES * EMB * 2;       // 19,200,000
    const size_t SZ_RP    = 600320;                          // 150017 ints, padded
    const size_t SZ_B     = 4096;
    const size_t NEEDED   = 2 * SZ_PAIRS + SZ_RP + 3 * SZ_B; // ~96.6 MB

    if (ws_size >= NEEDED) {
        char* w = (char*)d_ws;
        int2*    pairs2  = (int2*)(w);
        int2*    pairs1  = (int2*)(w + SZ_PAIRS);
        ushort4* curb    = (ushort4*)(w + SZ_PAIRS);                 // aliases pairs1
        ushort4* nxtb    = (ushort4*)(w + SZ_PAIRS + SZ_BF);         // aliases pairs1
        int*     row_cnt = (int*)(w + SZ_PAIRS + 40 * 1000 * 1000);  // pairs1 tail
        int*     row_ptr = (int*)(w + 2 * SZ_PAIRS);
        int*     bsum    = (int*)(w + 2 * SZ_PAIRS + SZ_RP);
        int*     boff    = (int*)(w + 2 * SZ_PAIRS + SZ_RP + SZ_B);
        int*     gcur    = (int*)(w + 2 * SZ_PAIRS + SZ_RP + 2 * SZ_B);

        // phase 0: row histogram -> row_ptr (+ bucket offsets boff, cursors gcur)
        k_zero<<<(NROWS_PAD + BLK - 1) / BLK, BLK, 0, stream>>>(row_cnt, NROWS_PAD);
        k_hist<<<grid_edge, BLK, 0, stream>>>(adj_dst, row_cnt);
        k_blocksum<<<NBUCKETS, BLK, 0, stream>>>(row_cnt, bsum);
        k_bscan<<<1, 1024, 0, stream>>>(bsum, boff, gcur);
        k_scan_final<<<NBUCKETS, BLK, 0, stream>>>(row_cnt, boff, row_ptr);

        // phase 1: bucket partition (row_cnt now dead; pairs1 overwritten)
        k_part<<<PART_BLOCKS, BLK, 0, stream>>>(adj_src, adj_dst, adj_vals, gcur, pairs1);

        // phase 2: single-pass per-bucket placement -> row-sorted pairs2
        k_sort<<<NBUCKETS, BLK, 0, stream>>>(boff, row_ptr, pairs1, pairs2);

        // phase 3: propagation (pairs1 region reused for bf16 node buffers)
        k_init<<<grid_node, BLK, 0, stream>>>(user_emb, item_emb, curb, (float4*)acc);
        k_spmm<<<grid_row16, BLK, 0, stream>>>(row_ptr, pairs2, curb, nxtb,
                                               (float4*)acc, 1.0f);
        k_spmm<<<grid_row16, BLK, 0, stream>>>(row_ptr, pairs2, nxtb, curb,
                                               (float4*)acc, 1.0f);
        k_spmm<<<grid_row16, BLK, 0, stream>>>(row_ptr, pairs2, curb, nxtb,
                                               (float4*)acc, 0.25f);
    } else {
        // R0 fallback: atomic scatter
        float* ws0 = (float*)d_ws;
        float* ws1 = ws0 + (size_t)N_NODES * EMB;
        lgcn_init<<<grid_node, BLK, 0, stream>>>(user_emb, item_emb,
                                                 (float4*)ws0, (float4*)ws1, (float4*)acc);
        lgcn_scatter<<<(N_EDGES*16+BLK-1)/BLK, BLK, 0, stream>>>(adj_src, adj_dst, adj_vals,
                                                    (const float4*)ws0, ws1);
        lgcn_add_zero<<<grid_node, BLK, 0, stream>>>((float4*)acc, (const float4*)ws1, (float4*)ws0);
        lgcn_scatter<<<(N_EDGES*16+BLK-1)/BLK, BLK, 0, stream>>>(adj_src, adj_dst, adj_vals,
                                                    (const float4*)ws1, ws0);
        lgcn_add_zero<<<grid_node, BLK, 0, stream>>>((float4*)acc, (const float4*)ws0, (float4*)ws1);
        lgcn_scatter<<<(N_EDGES*16+BLK-1)/BLK, BLK, 0, stream>>>(adj_src, adj_dst, adj_vals,
                                                    (const float4*)ws0, ws1);
        lgcn_final<<<grid_node, BLK, 0, stream>>>((float4*)acc, (const float4*)ws1);
    }
}

// Round 6
// 681.181 us; speedup vs baseline: 1.2945x; 1.2945x over previous
//
#include <hip/hip_runtime.h>

// LightGCN propagation on MI355X — R5: R3 pipeline structure + R4 kernel tuning.
//
// R4 post-mortem: global row histogram (6M device atomics on a 600KB array) =
// 233 us with 187 MB of HBM RMW write traffic — device-scope atomics are
// memory-side on MI355X. Revert to deriving row counts from pairs1 inside
// k_sort via native LDS int atomics (per-bucket 256-row histogram + scan),
// keeping R4's wins: 256-row buckets (shift math), PART_BLOCKS=512 (~160B
// runs -> low write amp), unroll-2 partition/placement, unroll-4 SpMM.
//
// Pipeline:
//   k_bhist  : per-block LDS bucket histogram -> global bucket counts (586 atomics/blk)
//   k_bscan  : exclusive scan -> bucket offsets boff + partition cursors gcur
//   k_part   : bucket partition, entry x = src | (dstLocal<<18), y = val bits
//   k_sort   : per-bucket LDS row histogram + scan -> row_ptr; place into pairs2
//   k_init   : acc=fp32 concat emb, curb=bf16 cast
//   k_spmm x3: 16 lanes/row bf16 gather, fp32 register accumulate, fused acc
//
// Inputs: [2] adj_src (6M int), [3] adj_dst (6M int), [4] adj_vals (6M f32),
//         [5] user_emb (100000x64 f32), [6] item_emb (50000x64 f32).
// Output: [150000x64] f32 = (e0+e1+e2+e3)/4.

#define NUM_USERS 100000
#define NUM_ITEMS 50000
#define N_NODES   150000
#define EMB       64
#define N_EDGES   6000000

#define ROWS_PER_B 256
#define NBUCKETS   586                        // ceil(150000/256)
#define NROWS_PAD  (NBUCKETS * ROWS_PER_B)    // 150016
#define PART_BLOCKS 512
#define CHUNK ((N_EDGES + PART_BLOCKS - 1) / PART_BLOCKS)   // 11719

constexpr int NODE_F4 = N_NODES * EMB / 4;   // 2,400,000
constexpr int USER_F4 = NUM_USERS * EMB / 4; // 1,600,000

__device__ __forceinline__ float bf2f(unsigned short u) {
    union { unsigned int i; float f; } x; x.i = ((unsigned int)u) << 16; return x.f;
}
__device__ __forceinline__ unsigned short f2bf(float f) {
    union { float f; unsigned int i; } x; x.f = f;
    unsigned int b = x.i;
    return (unsigned short)((b + 0x7FFFu + ((b >> 16) & 1u)) >> 16);  // RNE
}

// ---------------- phase 0: bucket histogram + scan ----------------

__global__ void k_zero(int* __restrict__ p, int n) {
    int i = blockIdx.x * blockDim.x + threadIdx.x;
    if (i < n) p[i] = 0;
}

__global__ __launch_bounds__(256) void k_bhist(const int* __restrict__ dst,
                                               int* __restrict__ gcnt) {
    __shared__ int cnt[NBUCKETS];
    int t = threadIdx.x;
    for (int i = t; i < NBUCKETS; i += 256) cnt[i] = 0;
    __syncthreads();
    int e0 = blockIdx.x * CHUNK;
    int e1 = min(e0 + CHUNK, N_EDGES);
    int e = e0 + t;
    for (; e + 256 < e1; e += 512) {
        int b0 = dst[e] >> 8;
        int b1 = dst[e + 256] >> 8;
        atomicAdd(&cnt[b0], 1);               // native ds_add_u32
        atomicAdd(&cnt[b1], 1);
    }
    if (e < e1) atomicAdd(&cnt[dst[e] >> 8], 1);
    __syncthreads();
    for (int i = t; i < NBUCKETS; i += 256)
        if (cnt[i]) atomicAdd(&gcnt[i], cnt[i]);   // only 586 global atomics/block
}

// one block of 1024: exclusive scan over bucket counts -> boff + gcur
__global__ void k_bscan(const int* __restrict__ gcnt, int* __restrict__ boff,
                        int* __restrict__ gcur) {
    __shared__ int s[1024];
    int t = threadIdx.x;
    int x = (t < NBUCKETS) ? gcnt[t] : 0;
    s[t] = x;
    __syncthreads();
    for (int off = 1; off < 1024; off <<= 1) {
        int v = (t >= off) ? s[t - off] : 0;
        __syncthreads();
        s[t] += v;
        __syncthreads();
    }
    if (t < NBUCKETS) { int ex = s[t] - x; boff[t] = ex; gcur[t] = ex; }
    if (t == 0) boff[NBUCKETS] = N_EDGES;
}

// ---------------- phase 1: bucket partition ----------------
// entry: x = src | (dstLocal<<18)  (src < 2^18, dstLocal < 256), y = val bits

__global__ __launch_bounds__(256) void k_part(const int* __restrict__ src,
                                              const int* __restrict__ dst,
                                              const float* __restrict__ val,
                                              int* __restrict__ gcur,
                                              int2* __restrict__ pairs) {
    __shared__ int cnt[NBUCKETS];
    __shared__ int base[NBUCKETS];
    int t = threadIdx.x;
    for (int i = t; i < NBUCKETS; i += 256) cnt[i] = 0;
    __syncthreads();
    int e0 = blockIdx.x * CHUNK;
    int e1 = min(e0 + CHUNK, N_EDGES);
    {
        int e = e0 + t;
        for (; e + 256 < e1; e += 512) {
            int b0 = dst[e] >> 8;
            int b1 = dst[e + 256] >> 8;
            atomicAdd(&cnt[b0], 1);
            atomicAdd(&cnt[b1], 1);
        }
        if (e < e1) atomicAdd(&cnt[dst[e] >> 8], 1);
    }
    __syncthreads();
    for (int i = t; i < NBUCKETS; i += 256) {
        int c = cnt[i];
        base[i] = c ? atomicAdd(&gcur[i], c) : 0;
        cnt[i] = 0;
    }
    __syncthreads();
    {
        int e = e0 + t;
        for (; e + 256 < e1; e += 512) {
            int d0 = dst[e];       int s0 = src[e];       float v0 = val[e];
            int d1 = dst[e + 256]; int s1 = src[e + 256]; float v1 = val[e + 256];
            int b0 = d0 >> 8, b1 = d1 >> 8;
            int o0 = atomicAdd(&cnt[b0], 1);
            int o1 = atomicAdd(&cnt[b1], 1);
            pairs[base[b0] + o0] = make_int2(s0 | ((d0 & 255) << 18), __float_as_int(v0));
            pairs[base[b1] + o1] = make_int2(s1 | ((d1 & 255) << 18), __float_as_int(v1));
        }
        if (e < e1) {
            int d0 = dst[e];
            int o0 = atomicAdd(&cnt[d0 >> 8], 1);
            pairs[base[d0 >> 8] + o0] = make_int2(src[e] | ((d0 & 255) << 18),
                                                  __float_as_int(val[e]));
        }
    }
}

// ---------------- phase 2: per-bucket row histogram + scan + placement ----------------

__global__ __launch_bounds__(256) void k_sort(const int* __restrict__ boff,
                                              const int2* __restrict__ pairs1,
                                              int2* __restrict__ pairs2,
                                              int* __restrict__ row_ptr) {
    __shared__ int cnt[ROWS_PER_B];    // row counts, then reused as cursors
    __shared__ int s[ROWS_PER_B];
    int b = blockIdx.x;
    int t = threadIdx.x;
    cnt[t] = 0;
    __syncthreads();
    int beg = boff[b], end = boff[b + 1];
    {
        int e = beg + t;
        for (; e + 256 < end; e += 512) {
            int r0 = ((unsigned)pairs1[e].x) >> 18;
            int r1 = ((unsigned)pairs1[e + 256].x) >> 18;
            atomicAdd(&cnt[r0], 1);          // native LDS int atomic
            atomicAdd(&cnt[r1], 1);
        }
        if (e < end) atomicAdd(&cnt[((unsigned)pairs1[e].x) >> 18], 1);
    }
    __syncthreads();
    int x = cnt[t];
    s[t] = x;
    __syncthreads();
    for (int off = 1; off < 256; off <<= 1) {
        int v = (t >= off) ? s[t - off] : 0;
        __syncthreads();
        s[t] += v;
        __syncthreads();
    }
    int ex = beg + s[t] - x;                  // exclusive prefix within bucket
    row_ptr[b * ROWS_PER_B + t] = ex;
    if (b == NBUCKETS - 1 && t == 255) row_ptr[NROWS_PAD] = N_EDGES;
    __syncthreads();                          // everyone sees cnt before overwrite
    cnt[t] = ex;                              // reuse as cursor
    __syncthreads();
    {
        int e = beg + t;
        for (; e + 256 < end; e += 512) {
            int2 p0 = pairs1[e];
            int2 p1 = pairs1[e + 256];
            int pos0 = atomicAdd(&cnt[((unsigned)p0.x) >> 18], 1);
            int pos1 = atomicAdd(&cnt[((unsigned)p1.x) >> 18], 1);
            pairs2[pos0] = make_int2(p0.x & 0x3FFFF, p0.y);
            pairs2[pos1] = make_int2(p1.x & 0x3FFFF, p1.y);
        }
        if (e < end) {
            int2 p0 = pairs1[e];
            int pos0 = atomicAdd(&cnt[((unsigned)p0.x) >> 18], 1);
            pairs2[pos0] = make_int2(p0.x & 0x3FFFF, p0.y);
        }
    }
}

// ---------------- phase 3: propagation ----------------

__global__ void k_init(const float4* __restrict__ ue, const float4* __restrict__ ie,
                       ushort4* __restrict__ curb, float4* __restrict__ acc) {
    int i = blockIdx.x * blockDim.x + threadIdx.x;
    if (i >= NODE_F4) return;
    float4 v = (i < USER_F4) ? ue[i] : ie[i - USER_F4];
    acc[i] = v;
    curb[i] = make_ushort4(f2bf(v.x), f2bf(v.y), f2bf(v.z), f2bf(v.w));
}

// 16 lanes per dst row; lane owns 4 channels. bf16 gather, fp32 reg accumulate.
__global__ __launch_bounds__(256) void k_spmm(const int* __restrict__ row_ptr,
                                              const int2* __restrict__ pairs,
                                              const ushort4* __restrict__ cur,
                                              ushort4* __restrict__ nxt,
                                              float4* __restrict__ acc, float s) {
    int tid = blockIdx.x * blockDim.x + threadIdx.x;
    int row = tid >> 4;
    if (row >= N_NODES) return;
    int c = tid & 15;
    int beg = row_ptr[row];
    int end = row_ptr[row + 1];
    float4 r = make_float4(0.f, 0.f, 0.f, 0.f);
    int k = beg;
    for (; k + 3 < end; k += 4) {
        int2 p0 = pairs[k];
        int2 p1 = pairs[k + 1];
        int2 p2 = pairs[k + 2];
        int2 p3 = pairs[k + 3];
        ushort4 g0 = cur[(long)p0.x * 16 + c];
        ushort4 g1 = cur[(long)p1.x * 16 + c];
        ushort4 g2 = cur[(long)p2.x * 16 + c];
        ushort4 g3 = cur[(long)p3.x * 16 + c];
        float v0 = __int_as_float(p0.y);
        float v1 = __int_as_float(p1.y);
        float v2 = __int_as_float(p2.y);
        float v3 = __int_as_float(p3.y);
        r.x += v0 * bf2f(g0.x) + v1 * bf2f(g1.x) + v2 * bf2f(g2.x) + v3 * bf2f(g3.x);
        r.y += v0 * bf2f(g0.y) + v1 * bf2f(g1.y) + v2 * bf2f(g2.y) + v3 * bf2f(g3.y);
        r.z += v0 * bf2f(g0.z) + v1 * bf2f(g1.z) + v2 * bf2f(g2.z) + v3 * bf2f(g3.z);
        r.w += v0 * bf2f(g0.w) + v1 * bf2f(g1.w) + v2 * bf2f(g2.w) + v3 * bf2f(g3.w);
    }
    for (; k < end; ++k) {
        int2 p0 = pairs[k];
        ushort4 g0 = cur[(long)p0.x * 16 + c];
        float v0 = __int_as_float(p0.y);
        r.x += v0 * bf2f(g0.x);
        r.y += v0 * bf2f(g0.y);
        r.z += v0 * bf2f(g0.z);
        r.w += v0 * bf2f(g0.w);
    }
    long o = (long)row * 16 + c;
    nxt[o] = make_ushort4(f2bf(r.x), f2bf(r.y), f2bf(r.z), f2bf(r.w));
    float4 a = acc[o];
    a.x = (a.x + r.x) * s;
    a.y = (a.y + r.y) * s;
    a.z = (a.z + r.z) * s;
    a.w = (a.w + r.w) * s;
    acc[o] = a;
}

// ---------------- R0 fallback (atomic scatter) for small ws ----------------

__global__ void lgcn_init(const float4* __restrict__ user_emb,
                          const float4* __restrict__ item_emb,
                          float4* __restrict__ cur, float4* __restrict__ nxt,
                          float4* __restrict__ acc) {
    int i = blockIdx.x * blockDim.x + threadIdx.x;
    if (i >= NODE_F4) return;
    float4 v = (i < USER_F4) ? user_emb[i] : item_emb[i - USER_F4];
    cur[i] = v; acc[i] = v; nxt[i] = make_float4(0.f, 0.f, 0.f, 0.f);
}

__global__ void lgcn_scatter(const int* __restrict__ src, const int* __restrict__ dst,
                             const float* __restrict__ val,
                             const float4* __restrict__ cur, float* __restrict__ nxt) {
    int tid = blockIdx.x * blockDim.x + threadIdx.x;
    int e = tid >> 4;
    if (e >= N_EDGES) return;
    int c = tid & 15;
    int s = src[e]; int d = dst[e]; float v = val[e];
    float4 m = cur[(long)s * 16 + c];
    float* p = nxt + (long)d * 64 + c * 4;
    unsafeAtomicAdd(p + 0, v * m.x);
    unsafeAtomicAdd(p + 1, v * m.y);
    unsafeAtomicAdd(p + 2, v * m.z);
    unsafeAtomicAdd(p + 3, v * m.w);
}

__global__ void lgcn_add_zero(float4* __restrict__ acc, const float4* __restrict__ nxt,
                              float4* __restrict__ other) {
    int i = blockIdx.x * blockDim.x + threadIdx.x;
    if (i >= NODE_F4) return;
    float4 a = acc[i]; float4 n = nxt[i];
    a.x += n.x; a.y += n.y; a.z += n.z; a.w += n.w;
    acc[i] = a;
    other[i] = make_float4(0.f, 0.f, 0.f, 0.f);
}

__global__ void lgcn_final(float4* __restrict__ acc, const float4* __restrict__ nxt) {
    int i = blockIdx.x * blockDim.x + threadIdx.x;
    if (i >= NODE_F4) return;
    float4 a = acc[i]; float4 n = nxt[i];
    a.x = (a.x + n.x) * 0.25f; a.y = (a.y + n.y) * 0.25f;
    a.z = (a.z + n.z) * 0.25f; a.w = (a.w + n.w) * 0.25f;
    acc[i] = a;
}

// ---------------- launch ----------------

extern "C" void kernel_launch(void* const* d_in, const int* in_sizes, int n_in,
                              void* d_out, int out_size, void* d_ws, size_t ws_size,
                              hipStream_t stream) {
    const int*    adj_src  = (const int*)d_in[2];
    const int*    adj_dst  = (const int*)d_in[3];
    const float*  adj_vals = (const float*)d_in[4];
    const float4* user_emb = (const float4*)d_in[5];
    const float4* item_emb = (const float4*)d_in[6];
    float* acc = (float*)d_out;

    const int BLK = 256;
    const int grid_node  = (NODE_F4 + BLK - 1) / BLK;        // 9375
    const int grid_row16 = (N_NODES * 16 + BLK - 1) / BLK;   // 9375

    // workspace layout (bytes):
    //   [0, 48MB)    pairs2
    //   [48, 96MB)   pairs1; after k_sort reused as curb (19.2MB) + nxtb (19.2MB)
    //   [96MB, ...)  row_ptr (150017 ints), gcnt, boff, gcur
    const size_t SZ_PAIRS = (size_t)N_EDGES * 8;             // 48,000,000
    const size_t SZ_BF    = (size_t)N_NODES * EMB * 2;       // 19,200,000
    const size_t SZ_RP    = 600320;                          // 150017 ints, padded
    const size_t SZ_B     = 4096;
    const size_t NEEDED   = 2 * SZ_PAIRS + SZ_RP + 3 * SZ_B; // ~96.6 MB

    if (ws_size >= NEEDED) {
        char* w = (char*)d_ws;
        int2*    pairs2  = (int2*)(w);
        int2*    pairs1  = (int2*)(w + SZ_PAIRS);
        ushort4* curb    = (ushort4*)(w + SZ_PAIRS);          // aliases pairs1
        ushort4* nxtb    = (ushort4*)(w + SZ_PAIRS + SZ_BF);  // aliases pairs1
        int*     row_ptr = (int*)(w + 2 * SZ_PAIRS);
        int*     gcnt    = (int*)(w + 2 * SZ_PAIRS + SZ_RP);
        int*     boff    = (int*)(w + 2 * SZ_PAIRS + SZ_RP + SZ_B);
        int*     gcur    = (int*)(w + 2 * SZ_PAIRS + SZ_RP + 2 * SZ_B);

        // phase 0: bucket counts (LDS-aggregated) -> offsets
        k_zero<<<(NBUCKETS + BLK - 1) / BLK, BLK, 0, stream>>>(gcnt, NBUCKETS);
        k_bhist<<<PART_BLOCKS, BLK, 0, stream>>>(adj_dst, gcnt);
        k_bscan<<<1, 1024, 0, stream>>>(gcnt, boff, gcur);

        // phase 1: bucket partition
        k_part<<<PART_BLOCKS, BLK, 0, stream>>>(adj_src, adj_dst, adj_vals, gcur, pairs1);

        // phase 2: per-bucket row sort -> pairs2 + row_ptr
        k_sort<<<NBUCKETS, BLK, 0, stream>>>(boff, pairs1, pairs2, row_ptr);

        // phase 3: propagation (pairs1 region reused for bf16 node buffers)
        k_init<<<grid_node, BLK, 0, stream>>>(user_emb, item_emb, curb, (float4*)acc);
        k_spmm<<<grid_row16, BLK, 0, stream>>>(row_ptr, pairs2, curb, nxtb,
                                               (float4*)acc, 1.0f);
        k_spmm<<<grid_row16, BLK, 0, stream>>>(row_ptr, pairs2, nxtb, curb,
                                               (float4*)acc, 1.0f);
        k_spmm<<<grid_row16, BLK, 0, stream>>>(row_ptr, pairs2, curb, nxtb,
                                               (float4*)acc, 0.25f);
    } else {
        // R0 fallback: atomic scatter
        float* ws0 = (float*)d_ws;
        float* ws1 = ws0 + (size_t)N_NODES * EMB;
        lgcn_init<<<grid_node, BLK, 0, stream>>>(user_emb, item_emb,
                                                 (float4*)ws0, (float4*)ws1, (float4*)acc);
        lgcn_scatter<<<(N_EDGES*16+BLK-1)/BLK, BLK, 0, stream>>>(adj_src, adj_dst, adj_vals,
                                                    (const float4*)ws0, ws1);
        lgcn_add_zero<<<grid_node, BLK, 0, stream>>>((float4*)acc, (const float4*)ws1, (float4*)ws0);
        lgcn_scatter<<<(N_EDGES*16+BLK-1)/BLK, BLK, 0, stream>>>(adj_src, adj_dst, adj_vals,
                                                    (const float4*)ws1, ws0);
        lgcn_add_zero<<<grid_node, BLK, 0, stream>>>((float4*)acc, (const float4*)ws0, (float4*)ws1);
        lgcn_scatter<<<(N_EDGES*16+BLK-1)/BLK, BLK, 0, stream>>>(adj_src, adj_dst, adj_vals,
                                                    (const float4*)ws0, ws1);
        lgcn_final<<<grid_node, BLK, 0, stream>>>((float4*)acc, (const float4*)ws1);
    }
}